// Round 2
// baseline (242.531 us; speedup 1.0000x reference)
//
#include <hip/hip_runtime.h>
#include <stdint.h>

#define B_ 2
#define T_ 2048
#define D_ 1024
#define H_ 16
#define DH_ 64
#define N3_ 3072
#define M_ 4096

typedef __attribute__((ext_vector_type(8))) short short8;
typedef __attribute__((ext_vector_type(4))) float f32x4;

typedef const uint32_t __attribute__((address_space(1))) gu32;
typedef uint32_t __attribute__((address_space(3))) lu32;

__device__ __forceinline__ void gload_lds16(const void* g, void* l) {
  __builtin_amdgcn_global_load_lds((gu32*)g, (lu32*)l, 16, 0, 0);
}

__device__ __forceinline__ uint16_t f2bf(float f) {
  union { float f; uint32_t u; } c; c.f = f;
  uint32_t u = c.u;
  return (uint16_t)((u + 0x7fffu + ((u >> 16) & 1u)) >> 16);
}

// ---------------- pre-pass: f32 -> bf16 convert ----------------
__global__ void k_convert(const float* __restrict__ in, uint16_t* __restrict__ out, int n) {
  int stride = gridDim.x * blockDim.x * 4;
  for (int i = (blockIdx.x * blockDim.x + threadIdx.x) * 4; i < n; i += stride) {
    float4 v = *reinterpret_cast<const float4*>(in + i);
    ushort4 ov;
    ov.x = f2bf(v.x); ov.y = f2bf(v.y); ov.z = f2bf(v.z); ov.w = f2bf(v.w);
    *reinterpret_cast<ushort4*>(out + i) = ov;
  }
}

// ---------------- pre-pass: transpose W [K][N] f32 -> Wt [N][K] bf16 ----------------
__global__ void k_transpose_bf(const float* __restrict__ W, uint16_t* __restrict__ Wt,
                               int K, int N) {
  __shared__ float tile[32][33];
  const int nb = blockIdx.x * 32, kb = blockIdx.y * 32;
  const int tx = threadIdx.x, ty = threadIdx.y;  // (32,8)
#pragma unroll
  for (int i = 0; i < 4; i++)
    tile[ty + i * 8][tx] = W[(size_t)(kb + ty + i * 8) * N + nb + tx];
  __syncthreads();
#pragma unroll
  for (int i = 0; i < 4; i++) {
    const int nl = ty + i * 8;
    Wt[(size_t)(nb + nl) * K + kb + tx] = f2bf(tile[tx][nl]);
  }
}

// ---------------- GEMM: C[M][N] = A[M][K](bf16) * Bt[N][K](bf16)^T + bias ----------------
template <bool OUT_BF16>
__global__ __launch_bounds__(256)
void k_gemm_bt(const uint16_t* __restrict__ A, const uint16_t* __restrict__ Bt,
               const float* __restrict__ bias, void* __restrict__ Cv,
               int M, int N, int K) {
  constexpr int BK = 32;
  __shared__ uint16_t As[128 * BK];
  __shared__ uint16_t Bs[128 * BK];
  const int tid = threadIdx.x;
  const int w = tid >> 6, lane = tid & 63;
  const int l16 = lane & 15, lg = lane >> 4;
  const int bm = blockIdx.x * 128, bn = blockIdx.y * 128;
  const int wr = (w >> 1) * 64, wc = (w & 1) * 64;
  f32x4 acc[4][4] = {};
  for (int kt = 0; kt < K; kt += BK) {
    __syncthreads();
#pragma unroll
    for (int j = 0; j < 2; j++) {
      const int slot = j * 4 + w;
      const int bbyte = slot * 1024 + lane * 16;
      const int row = bbyte >> 6;          // 64 bytes per LDS row (32 bf16)
      const int cole = (bbyte & 63) >> 1;  // element offset in row
      gload_lds16(A + (size_t)(bm + row) * K + kt + cole, (char*)As + slot * 1024);
      gload_lds16(Bt + (size_t)(bn + row) * K + kt + cole, (char*)Bs + slot * 1024);
    }
    __syncthreads();
    short8 aF[4], bF[4];
#pragma unroll
    for (int f = 0; f < 4; f++) {
      aF[f] = *(const short8*)(As + (wr + f * 16 + l16) * BK + lg * 8);
      bF[f] = *(const short8*)(Bs + (wc + f * 16 + l16) * BK + lg * 8);
    }
#pragma unroll
    for (int mf = 0; mf < 4; mf++)
#pragma unroll
      for (int nf = 0; nf < 4; nf++)
        acc[mf][nf] = __builtin_amdgcn_mfma_f32_16x16x32_bf16(aF[mf], bF[nf], acc[mf][nf], 0, 0, 0);
  }
#pragma unroll
  for (int nf = 0; nf < 4; nf++) {
    const int col = bn + wc + nf * 16 + l16;
    const float bv = bias ? bias[col] : 0.0f;
#pragma unroll
    for (int mf = 0; mf < 4; mf++) {
      const int row0 = bm + wr + mf * 16 + lg * 4;
#pragma unroll
      for (int r = 0; r < 4; r++) {
        const float v = acc[mf][nf][r] + bv;
        if (OUT_BF16)
          ((uint16_t*)Cv)[(size_t)(row0 + r) * N + col] = f2bf(v);
        else
          ((float*)Cv)[(size_t)(row0 + r) * N + col] = v;
      }
    }
  }
}

// ---------------- flash attention with sink ----------------
// qkv: [B,T,3*H*DH] bf16. z: [B,T,H*DH] bf16.
// block = (64 q-rows) x (one b,h). 4 waves, 16 q-rows each.
__global__ __launch_bounds__(256)
void k_attn(const uint16_t* __restrict__ qkv, const float* __restrict__ sink,
            uint16_t* __restrict__ z) {
  constexpr int KP = 72;  // padded row length (elements) -> 144B stride
  __shared__ uint16_t Ks[64 * KP];      // [key][d]
  __shared__ uint16_t Vt[64 * KP];      // [d][key]  (transposed)
  __shared__ uint16_t Ps[4][16 * KP];   // per-wave P [qrow][key]
  const int qblk = blockIdx.x, bh = blockIdx.y;
  const int b = bh >> 4, h = bh & 15;
  const int tid = threadIdx.x, w = tid >> 6, lane = tid & 63;
  const int l16 = lane & 15, lg = lane >> 4;
  const uint16_t* Qg = qkv + (size_t)b * T_ * N3_ + h * DH_;
  const uint16_t* Kg = Qg + H_ * DH_;
  const uint16_t* Vg = Qg + 2 * H_ * DH_;
  const int q0 = qblk * 64 + w * 16;
  short8 qA[2];
#pragma unroll
  for (int kf = 0; kf < 2; kf++)
    qA[kf] = *(const short8*)(Qg + (size_t)(q0 + l16) * N3_ + kf * 32 + lg * 8);
  const float sk = sink[h];
  float m_r[4] = {sk, sk, sk, sk};   // sink = initial online-softmax state
  float l_r[4] = {1.f, 1.f, 1.f, 1.f};
  f32x4 o[4] = {};
  // staging: 8 threads per 64-elem row, 32 rows per pass, 2 passes = full 64x64 tile
  const int srow = tid >> 3, schunk = (tid & 7) * 8;
  const int ntiles = qblk + 1;
  for (int kt = 0; kt < ntiles; kt++) {
    __syncthreads();
#pragma unroll
    for (int half = 0; half < 2; half++) {
      const int row = half * 32 + srow;
      const size_t grow = (size_t)(kt * 64 + row) * N3_ + schunk;
      short8 kv = *(const short8*)(Kg + grow);
      *(short8*)(Ks + row * KP + schunk) = kv;
      short8 vv = *(const short8*)(Vg + grow);
#pragma unroll
      for (int j = 0; j < 8; j++)
        Vt[(schunk + j) * KP + row] = (uint16_t)vv[j];
    }
    __syncthreads();
    // S = Q K^T  (16 q-rows x 64 keys per wave)
    f32x4 s[4];
#pragma unroll
    for (int nf = 0; nf < 4; nf++) {
      short8 kB0 = *(const short8*)(Ks + (nf * 16 + l16) * KP + lg * 8);
      short8 kB1 = *(const short8*)(Ks + (nf * 16 + l16) * KP + 32 + lg * 8);
      f32x4 t = {};
      t = __builtin_amdgcn_mfma_f32_16x16x32_bf16(qA[0], kB0, t, 0, 0, 0);
      t = __builtin_amdgcn_mfma_f32_16x16x32_bf16(qA[1], kB1, t, 0, 0, 0);
      s[nf] = t;
    }
    const bool diag = (kt == qblk);
#pragma unroll
    for (int r = 0; r < 4; r++) {
      const int qa = q0 + lg * 4 + r;
      float sv[4];
      float rowm = -3e38f;
#pragma unroll
      for (int nf = 0; nf < 4; nf++) {
        float x = s[nf][r] * 0.125f;
        if (diag && (kt * 64 + nf * 16 + l16) > qa) x = -3e38f;
        sv[nf] = x;
        rowm = fmaxf(rowm, x);
      }
#pragma unroll
      for (int msk = 1; msk < 16; msk <<= 1) rowm = fmaxf(rowm, __shfl_xor(rowm, msk));
      const float mnew = fmaxf(m_r[r], rowm);
      const float alpha = __expf(m_r[r] - mnew);
      float psum = 0.f;
#pragma unroll
      for (int nf = 0; nf < 4; nf++) {
        const float p = __expf(sv[nf] - mnew);
        psum += p;
        Ps[w][(lg * 4 + r) * KP + nf * 16 + l16] = f2bf(p);
      }
#pragma unroll
      for (int msk = 1; msk < 16; msk <<= 1) psum += __shfl_xor(psum, msk);
      l_r[r] = l_r[r] * alpha + psum;
      m_r[r] = mnew;
#pragma unroll
      for (int df = 0; df < 4; df++) o[df][r] *= alpha;
    }
    // O += P V
#pragma unroll
    for (int ks = 0; ks < 2; ks++) {
      short8 pA = *(const short8*)(&Ps[w][l16 * KP + ks * 32 + lg * 8]);
#pragma unroll
      for (int df = 0; df < 4; df++) {
        short8 vB = *(const short8*)(Vt + (df * 16 + l16) * KP + ks * 32 + lg * 8);
        o[df] = __builtin_amdgcn_mfma_f32_16x16x32_bf16(pA, vB, o[df], 0, 0, 0);
      }
    }
  }
#pragma unroll
  for (int r = 0; r < 4; r++) {
    const float inv = 1.f / l_r[r];
    const int qa = q0 + lg * 4 + r;
    uint16_t* zp = z + (size_t)(b * T_ + qa) * (H_ * DH_) + h * DH_;
#pragma unroll
    for (int df = 0; df < 4; df++) zp[df * 16 + l16] = f2bf(o[df][r] * inv);
  }
}

extern "C" void kernel_launch(void* const* d_in, const int* in_sizes, int n_in,
                              void* d_out, int out_size, void* d_ws, size_t ws_size,
                              hipStream_t stream) {
  const float* x    = (const float*)d_in[0];
  const float* Wqkv = (const float*)d_in[1];
  const float* bqkv = (const float*)d_in[2];
  const float* Wo   = (const float*)d_in[3];
  const float* bo   = (const float*)d_in[4];
  const float* sink = (const float*)d_in[5];

  char* ws = (char*)d_ws;
  uint16_t* xb    = (uint16_t*)(ws);                        //  8 MB: x bf16 [4096][1024]
  uint16_t* wqkvt = (uint16_t*)(ws + (size_t)8  * 1048576); //  6 MB: W_QKV^T bf16 [3072][1024]
  uint16_t* wot   = (uint16_t*)(ws + (size_t)14 * 1048576); //  2 MB: W_O^T bf16 [1024][1024]
  uint16_t* qkvb  = (uint16_t*)(ws + (size_t)16 * 1048576); // 24 MB: qkv bf16 [4096][3072]
  uint16_t* zb    = (uint16_t*)(ws + (size_t)40 * 1048576); //  8 MB: z bf16 [4096][1024]

  k_convert<<<2048, 256, 0, stream>>>(x, xb, M_ * D_);
  k_transpose_bf<<<dim3(N3_ / 32, D_ / 32), dim3(32, 8), 0, stream>>>(Wqkv, wqkvt, D_, N3_);
  k_transpose_bf<<<dim3(D_ / 32, D_ / 32), dim3(32, 8), 0, stream>>>(Wo, wot, D_, D_);

  k_gemm_bt<true><<<dim3(M_ / 128, N3_ / 128), 256, 0, stream>>>(xb, wqkvt, bqkv, qkvb, M_, N3_, D_);
  k_attn<<<dim3(T_ / 64, B_ * H_), 256, 0, stream>>>(qkvb, sink, zb);
  k_gemm_bt<false><<<dim3(M_ / 128, D_ / 128), 256, 0, stream>>>(zb, wot, bo, d_out, M_, D_, D_);
}

// Round 3
// 151.042 us; speedup vs baseline: 1.6057x; 1.6057x over previous
//
#include <hip/hip_runtime.h>
#include <stdint.h>

#define B_ 2
#define T_ 2048
#define D_ 1024
#define H_ 16
#define DH_ 64
#define N3_ 3072
#define M_ 4096

typedef __attribute__((ext_vector_type(8))) short short8;
typedef __attribute__((ext_vector_type(4))) float f32x4;

typedef const uint32_t __attribute__((address_space(1))) gu32;
typedef uint32_t __attribute__((address_space(3))) lu32;

__device__ __forceinline__ void gload_lds16(const void* g, void* l) {
  __builtin_amdgcn_global_load_lds((gu32*)g, (lu32*)l, 16, 0, 0);
}

__device__ __forceinline__ uint16_t f2bf(float f) {
  union { float f; uint32_t u; } c; c.f = f;
  uint32_t u = c.u;
  return (uint16_t)((u + 0x7fffu + ((u >> 16) & 1u)) >> 16);
}

__device__ __forceinline__ uint32_t cvtpk_bf16(float lo, float hi) {
  uint32_t r;
  asm("v_cvt_pk_bf16_f32 %0, %1, %2" : "=v"(r) : "v"(lo), "v"(hi));
  return r;
}

// ---------------- pre-pass: f32 -> bf16 convert ----------------
__global__ void k_convert(const float* __restrict__ in, uint16_t* __restrict__ out, int n) {
  int stride = gridDim.x * blockDim.x * 4;
  for (int i = (blockIdx.x * blockDim.x + threadIdx.x) * 4; i < n; i += stride) {
    float4 v = *reinterpret_cast<const float4*>(in + i);
    ushort4 ov;
    ov.x = f2bf(v.x); ov.y = f2bf(v.y); ov.z = f2bf(v.z); ov.w = f2bf(v.w);
    *reinterpret_cast<ushort4*>(out + i) = ov;
  }
}

// ---------------- pre-pass: transpose W [K][N] f32 -> Wt [N][K] bf16 ----------------
__global__ void k_transpose_bf(const float* __restrict__ W, uint16_t* __restrict__ Wt,
                               int K, int N) {
  __shared__ float tile[32][33];
  const int nb = blockIdx.x * 32, kb = blockIdx.y * 32;
  const int tx = threadIdx.x, ty = threadIdx.y;  // (32,8)
#pragma unroll
  for (int i = 0; i < 4; i++)
    tile[ty + i * 8][tx] = W[(size_t)(kb + ty + i * 8) * N + nb + tx];
  __syncthreads();
#pragma unroll
  for (int i = 0; i < 4; i++) {
    const int nl = ty + i * 8;
    Wt[(size_t)(nb + nl) * K + kb + tx] = f2bf(tile[tx][nl]);
  }
}

// ---------------- pre-pass: V from qkv [t][d] -> Vt [bh][d][t] bf16 ----------------
__global__ __launch_bounds__(256)
void k_vtrans(const uint16_t* __restrict__ qkv, uint16_t* __restrict__ vt) {
  __shared__ uint16_t tl[64 * 64];
  const int tb = blockIdx.x, bh = blockIdx.y;
  const int b = bh >> 4, h = bh & 15;
  const uint16_t* Vg = qkv + (size_t)b * T_ * N3_ + 2 * H_ * DH_ + h * DH_;
  const int tid = threadIdx.x;
#pragma unroll
  for (int p = 0; p < 2; p++) {
    const int ch = p * 256 + tid;
    const int row = ch >> 3, cg = ch & 7;
    short8 v = *(const short8*)(Vg + (size_t)(tb * 64 + row) * N3_ + cg * 8);
    *(short8*)&tl[row * 64 + (cg ^ (row & 7)) * 8] = v;  // swizzled store
  }
  __syncthreads();
#pragma unroll
  for (int p = 0; p < 2; p++) {
    const int och = p * 256 + tid;
    const int d = och >> 3, ct = och & 7;
    ushort4 lo, hi;
    uint16_t tmp[8];
#pragma unroll
    for (int j = 0; j < 8; j++) {
      const int row = ct * 8 + j;
      tmp[j] = tl[row * 64 + ((d >> 3) ^ (row & 7)) * 8 + (d & 7)];
    }
    short8 ov;
#pragma unroll
    for (int j = 0; j < 8; j++) ov[j] = (short)tmp[j];
    *(short8*)(vt + (size_t)bh * DH_ * T_ + (size_t)d * T_ + tb * 64 + ct * 8) = ov;
  }
}

// ---------------- GEMM: C[M][N] = A[M][K](bf16) * Bt[N][K](bf16)^T + bias ----------------
template <bool OUT_BF16>
__global__ __launch_bounds__(256)
void k_gemm_bt(const uint16_t* __restrict__ A, const uint16_t* __restrict__ Bt,
               const float* __restrict__ bias, void* __restrict__ Cv,
               int M, int N, int K) {
  constexpr int BK = 32;
  __shared__ uint16_t As[128 * BK];
  __shared__ uint16_t Bs[128 * BK];
  const int tid = threadIdx.x;
  const int w = tid >> 6, lane = tid & 63;
  const int l16 = lane & 15, lg = lane >> 4;
  const int bm = blockIdx.x * 128, bn = blockIdx.y * 128;
  const int wr = (w >> 1) * 64, wc = (w & 1) * 64;
  f32x4 acc[4][4] = {};
  for (int kt = 0; kt < K; kt += BK) {
    __syncthreads();
#pragma unroll
    for (int j = 0; j < 2; j++) {
      const int slot = j * 4 + w;
      const int bbyte = slot * 1024 + lane * 16;
      const int row = bbyte >> 6;
      const int cole = (bbyte & 63) >> 1;
      gload_lds16(A + (size_t)(bm + row) * K + kt + cole, (char*)As + slot * 1024);
      gload_lds16(Bt + (size_t)(bn + row) * K + kt + cole, (char*)Bs + slot * 1024);
    }
    __syncthreads();
    short8 aF[4], bF[4];
#pragma unroll
    for (int f = 0; f < 4; f++) {
      aF[f] = *(const short8*)(As + (wr + f * 16 + l16) * BK + lg * 8);
      bF[f] = *(const short8*)(Bs + (wc + f * 16 + l16) * BK + lg * 8);
    }
#pragma unroll
    for (int mf = 0; mf < 4; mf++)
#pragma unroll
      for (int nf = 0; nf < 4; nf++)
        acc[mf][nf] = __builtin_amdgcn_mfma_f32_16x16x32_bf16(aF[mf], bF[nf], acc[mf][nf], 0, 0, 0);
  }
#pragma unroll
  for (int nf = 0; nf < 4; nf++) {
    const int col = bn + wc + nf * 16 + l16;
    const float bv = bias ? bias[col] : 0.0f;
#pragma unroll
    for (int mf = 0; mf < 4; mf++) {
      const int row0 = bm + wr + mf * 16 + lg * 4;
#pragma unroll
      for (int r = 0; r < 4; r++) {
        const float v = acc[mf][nf][r] + bv;
        if (OUT_BF16)
          ((uint16_t*)Cv)[(size_t)(row0 + r) * N + col] = f2bf(v);
        else
          ((float*)Cv)[(size_t)(row0 + r) * N + col] = v;
      }
    }
  }
}

// ---------------- flash attention v2: swapped QK^T, in-reg softmax ----------------
// Block jp handles q-blocks {jp, 31-jp} for one (b,h): balanced 33 tile-units.
// 4 waves x 16 q-rows per q-set. K,Vt staged via global_load_lds with
// source-side XOR chunk swizzle; reads use matching swizzle (conflict-free).
__global__ __launch_bounds__(256)
void k_attn2(const uint16_t* __restrict__ qkv, const uint16_t* __restrict__ vt,
             const float* __restrict__ sink, uint16_t* __restrict__ z) {
  __shared__ uint16_t Ks[2][64 * 64];
  __shared__ uint16_t Vs[2][64 * 64];
  __shared__ uint16_t Ps[4][16 * 64];
  const int jp = blockIdx.x, bh = blockIdx.y;
  const int b = bh >> 4, h = bh & 15;
  const int tid = threadIdx.x, w = tid >> 6;
  const int lane = tid & 63, l16 = lane & 15, lg = lane >> 4;
  const uint16_t* Qg = qkv + (size_t)b * T_ * N3_ + h * DH_;
  const uint16_t* Kg = Qg + H_ * DH_;
  const uint16_t* Vtg = vt + (size_t)bh * DH_ * T_;
  const int qblk[2] = {jp, 31 - jp};
  const int ntiles = 32 - jp;  // qblk[1]+1
  // Q fragments (second mfma operand): Q[q = l16][dh = kf*32 + lg*8 + j]
  short8 qF[2][2];
#pragma unroll
  for (int qs = 0; qs < 2; qs++)
#pragma unroll
    for (int kf = 0; kf < 2; kf++)
      qF[qs][kf] = *(const short8*)(Qg + (size_t)(qblk[qs] * 64 + w * 16 + l16) * N3_ + kf * 32 + lg * 8);
  const float c2 = 0.125f * 1.44269504f;  // scale * log2(e)
  const float sk2 = sink[h] * 1.44269504f;
  float m2[2] = {sk2, sk2};  // sink folded into initial online-softmax state
  float l_[2] = {1.f, 1.f};
  f32x4 o[2][4] = {};

  auto STAGE = [&](int buf, int kt) {
#pragma unroll
    for (int p = 0; p < 2; p++) {
      const int chunk = p * 256 + tid;
      const int row = chunk >> 3, c = chunk & 7;
      const int cg = c ^ (row & 7);  // pre-swizzled global source (m173)
      gload_lds16(Kg + (size_t)(kt * 64 + row) * N3_ + cg * 8,
                  (char*)&Ks[buf][0] + (p * 256 + w * 64) * 16);
      gload_lds16(Vtg + (size_t)row * T_ + kt * 64 + cg * 8,
                  (char*)&Vs[buf][0] + (p * 256 + w * 64) * 16);
    }
  };

  STAGE(0, 0);
  __syncthreads();
  int cur = 0;
  for (int kt = 0; kt < ntiles; kt++) {
    if (kt + 1 < ntiles) STAGE(cur ^ 1, kt + 1);  // async: flies during compute
    // K fragments (first operand): K[key = nf*16+l16][dh = kf*32 + lg*8 + j]
    short8 kF[2][4];
#pragma unroll
    for (int kf = 0; kf < 2; kf++)
#pragma unroll
      for (int nf = 0; nf < 4; nf++) {
        const int row = nf * 16 + l16;
        const int cc = (kf * 4 + lg) ^ (l16 & 7);
        kF[kf][nf] = *(const short8*)(&Ks[cur][0] + row * 64 + cc * 8);
      }
#pragma unroll
    for (int qs = 0; qs < 2; qs++) {
      if (qs == 0 && kt > qblk[0]) continue;  // block-uniform branch
      // S^T = K Q^T: s[nf] holds S[key = kt*64+nf*16+lg*4+r][q = qb+l16]
      f32x4 s[4];
#pragma unroll
      for (int nf = 0; nf < 4; nf++) {
        f32x4 t = {};
        t = __builtin_amdgcn_mfma_f32_16x16x32_bf16(kF[0][nf], qF[qs][0], t, 0, 0, 0);
        t = __builtin_amdgcn_mfma_f32_16x16x32_bf16(kF[1][nf], qF[qs][1], t, 0, 0, 0);
        s[nf] = t;
      }
      const int qb = qblk[qs] * 64 + w * 16;
      const bool diag = (kt == qblk[qs]);
      float mt = -3e38f;
      if (diag) {
#pragma unroll
        for (int nf = 0; nf < 4; nf++)
#pragma unroll
          for (int r = 0; r < 4; r++) {
            float v = s[nf][r] * c2;
            if (kt * 64 + nf * 16 + lg * 4 + r > qb + l16) v = -3e38f;
            s[nf][r] = v;
            mt = fmaxf(mt, v);
          }
      } else {
#pragma unroll
        for (int nf = 0; nf < 4; nf++)
#pragma unroll
          for (int r = 0; r < 4; r++) {
            const float v = s[nf][r] * c2;
            s[nf][r] = v;
            mt = fmaxf(mt, v);
          }
      }
      mt = fmaxf(mt, __shfl_xor(mt, 16));
      mt = fmaxf(mt, __shfl_xor(mt, 32));
      const float mnew = fmaxf(m2[qs], mt);
      const float alpha = exp2f(m2[qs] - mnew);
      m2[qs] = mnew;
      float ps = 0.f;
#pragma unroll
      for (int nf = 0; nf < 4; nf++)
#pragma unroll
        for (int r = 0; r < 4; r++) {
          const float p = exp2f(s[nf][r] - mnew);
          s[nf][r] = p;
          ps += p;
        }
      ps += __shfl_xor(ps, 16);
      ps += __shfl_xor(ps, 32);
      l_[qs] = l_[qs] * alpha + ps;
      // pack P -> per-wave LDS (swizzled b64 writes)
#pragma unroll
      for (int nf = 0; nf < 4; nf++) {
        uint2 pw;
        pw.x = cvtpk_bf16(s[nf][0], s[nf][1]);
        pw.y = cvtpk_bf16(s[nf][2], s[nf][3]);
        const int cc = (nf * 2 + (lg >> 1)) ^ (l16 & 7);
        *(uint2*)((char*)&Ps[w][0] + l16 * 128 + cc * 16 + (lg & 1) * 8) = pw;
      }
      // rescale O (alpha lives at lanes l16==q; O's q = lg*4+r)
      float ar[4];
#pragma unroll
      for (int r = 0; r < 4; r++) ar[r] = __shfl(alpha, lg * 4 + r);
#pragma unroll
      for (int df = 0; df < 4; df++)
#pragma unroll
        for (int r = 0; r < 4; r++) o[qs][df][r] *= ar[r];
      // O += P V : P[q=l16][key=lg*8+j], V[d=l16][key=lg*8+j]
#pragma unroll
      for (int ks = 0; ks < 2; ks++) {
        const int cp = (ks * 4 + lg) ^ (l16 & 7);
        const short8 pF = *(const short8*)((char*)&Ps[w][0] + l16 * 128 + cp * 16);
#pragma unroll
        for (int df = 0; df < 4; df++) {
          const short8 vF = *(const short8*)((char*)&Vs[cur][0] + (df * 16 + l16) * 128 + cp * 16);
          o[qs][df] = __builtin_amdgcn_mfma_f32_16x16x32_bf16(pF, vF, o[qs][df], 0, 0, 0);
        }
      }
    }
    __syncthreads();
    cur ^= 1;
  }
  // epilogue: normalize (l lives at lanes l16==q; O's q = lg*4+r) and store
#pragma unroll
  for (int qs = 0; qs < 2; qs++) {
#pragma unroll
    for (int r = 0; r < 4; r++) {
      const float inv = 1.f / __shfl(l_[qs], lg * 4 + r);
      const int qa = qblk[qs] * 64 + w * 16 + lg * 4 + r;
      uint16_t* zp = z + (size_t)(b * T_ + qa) * (H_ * DH_) + h * DH_;
#pragma unroll
      for (int df = 0; df < 4; df++) zp[df * 16 + l16] = f2bf(o[qs][df][r] * inv);
    }
  }
}

extern "C" void kernel_launch(void* const* d_in, const int* in_sizes, int n_in,
                              void* d_out, int out_size, void* d_ws, size_t ws_size,
                              hipStream_t stream) {
  const float* x    = (const float*)d_in[0];
  const float* Wqkv = (const float*)d_in[1];
  const float* bqkv = (const float*)d_in[2];
  const float* Wo   = (const float*)d_in[3];
  const float* bo   = (const float*)d_in[4];
  const float* sink = (const float*)d_in[5];

  char* ws = (char*)d_ws;
  uint16_t* xb    = (uint16_t*)(ws);                        //  8 MB: x bf16; dead after gemm1
  uint16_t* vtb   = (uint16_t*)(ws);                        //  8 MB: Vt[bh][d][t] (aliases xb)
  uint16_t* wqkvt = (uint16_t*)(ws + (size_t)8  * 1048576); //  6 MB: W_QKV^T bf16
  uint16_t* wot   = (uint16_t*)(ws + (size_t)14 * 1048576); //  2 MB: W_O^T bf16
  uint16_t* qkvb  = (uint16_t*)(ws + (size_t)16 * 1048576); // 24 MB: qkv bf16
  uint16_t* zb    = (uint16_t*)(ws + (size_t)40 * 1048576); //  8 MB: z bf16

  k_convert<<<2048, 256, 0, stream>>>(x, xb, M_ * D_);
  k_transpose_bf<<<dim3(N3_ / 32, D_ / 32), dim3(32, 8), 0, stream>>>(Wqkv, wqkvt, D_, N3_);
  k_transpose_bf<<<dim3(D_ / 32, D_ / 32), dim3(32, 8), 0, stream>>>(Wo, wot, D_, D_);

  k_gemm_bt<true><<<dim3(M_ / 128, N3_ / 128), 256, 0, stream>>>(xb, wqkvt, bqkv, qkvb, M_, N3_, D_);
  k_vtrans<<<dim3(T_ / 64, B_ * H_), 256, 0, stream>>>(qkvb, vtb);
  k_attn2<<<dim3(16, B_ * H_), 256, 0, stream>>>(qkvb, vtb, sink, zb);
  k_gemm_bt<false><<<dim3(M_ / 128, D_ / 128), 256, 0, stream>>>(zb, wot, bo, d_out, M_, D_, D_);
}